// Round 2
// baseline (227.558 us; speedup 1.0000x reference)
//
#include <hip/hip_runtime.h>
#include <stdint.h>

// Problem constants (from reference setup_inputs)
#define BNUM  8192
#define LROWS 32
#define MLAB  32
#define CCLS  96
#define WPB   4              // waves per block
#define SPW   2              // samples per wave (one per 32-lane half)
#define SPB   (WPB*SPW)      // 8 samples per block
#define NBLK  (BNUM/SPB)     // 1024 blocks

// Design (round N+1):
//  P1 (lane-per-row): lane u owns row u of its half's sample. Two 12x float4
//     register batches deepen the VMEM pipeline; serial argmax
//     (first-occurrence) + sumexp math is BIT-IDENTICAL to the verified
//     kernel. Writes {lse, (float)pred} to lpS (8 B/row).
//  Phase B: DP wavefront. The 32 KB ceTab + P3 staging phase are GONE:
//     per step, {lse,pred} comes from lpS (ds_read_b64) and x[i-1,lab_j]
//     straight from L1/L2 (sample is cache-warm from P1). Both operand
//     fetches depend only on (d,lane) -> off the serial chain, prefetched
//     across the unroll-8 window.
//  The loop-carried chain itself now runs through DPP wave_shr:1 (full-rate
//     VALU lane shift) instead of ds_bpermute __shfl_up — removes ~100 cy of
//     DS latency per step from a 64-step serial recurrence.
__device__ __forceinline__ int dpp_wshr1_i32(int v) {
    // dpp_ctrl 0x138 = wave_shr:1 (gfx9/CDNA DPP): lane n <- lane n-1,
    // lane 0 <- 0 (bound_ctrl). Lanes 0 and 32 are overridden by the
    // analytic column-0 injection below, matching old __shfl_up width-64.
    return __builtin_amdgcn_update_dpp(0, v, 0x138, 0xF, 0xF, true);
}
__device__ __forceinline__ float dpp_wshr1_f32(float v) {
    return __int_as_float(
        __builtin_amdgcn_update_dpp(0, __float_as_int(v), 0x138, 0xF, 0xF, true));
}

__global__ __launch_bounds__(256, 4) void editloss_main(
    const float* __restrict__ x, const int* __restrict__ y,
    float* __restrict__ partial_sum, float* __restrict__ partial_cnt)
{
    __shared__ float2 lpS[SPB][LROWS];   // {lse, (float)pred} — 2 KB
    __shared__ float  psum[SPB];
    __shared__ float  pcnt[SPB];

    const int w    = threadIdx.x >> 6;
    const int lane = threadIdx.x & 63;
    const int g    = lane >> 5;          // which sample of the wave
    const int u    = lane & 31;          // slot within 32-lane half
    const int s    = w * SPW + g;        // sample slot in block [0,8)
    const int sb   = blockIdx.x * SPB + s;

    const float* xs    = x + (size_t)sb * (LROWS * CCLS);
    const int    lab_u = y[sb * MLAB + u];

    // ---------- P1: lane-per-row argmax + logsumexp (math identical) -------
    {
        const float4* rowv = (const float4*)(xs + (size_t)u * CCLS);
        float bmax[4]; int bidx[4]; float bsum[4];
#pragma unroll
        for (int c = 0; c < 4; ++c) { bmax[c] = -1e30f; bidx[c] = 0; bsum[c] = 0.f; }

        // batch A: elements 0..47 (accumulator blocks c=0,1)
        float4 va[12];
#pragma unroll
        for (int t = 0; t < 12; ++t) va[t] = rowv[t];
#pragma unroll
        for (int t = 0; t < 12; ++t) {
            const int c = t / 6;                  // compile-time per unrolled t
            const float4 v = va[t];
            const int base = t * 4;
            // ascending scan, strict '>' keeps first occurrence
            if (v.x > bmax[c]) { bmax[c] = v.x; bidx[c] = base + 0; }
            if (v.y > bmax[c]) { bmax[c] = v.y; bidx[c] = base + 1; }
            if (v.z > bmax[c]) { bmax[c] = v.z; bidx[c] = base + 2; }
            if (v.w > bmax[c]) { bmax[c] = v.w; bidx[c] = base + 3; }
            bsum[c] += __expf(v.x) + __expf(v.y) + __expf(v.z) + __expf(v.w);
        }
        // batch B: elements 48..95 (accumulator blocks c=2,3)
        float4 vb[12];
#pragma unroll
        for (int t = 0; t < 12; ++t) vb[t] = rowv[12 + t];
#pragma unroll
        for (int t = 0; t < 12; ++t) {
            const int c = 2 + t / 6;
            const float4 v = vb[t];
            const int base = (12 + t) * 4;
            if (v.x > bmax[c]) { bmax[c] = v.x; bidx[c] = base + 0; }
            if (v.y > bmax[c]) { bmax[c] = v.y; bidx[c] = base + 1; }
            if (v.z > bmax[c]) { bmax[c] = v.z; bidx[c] = base + 2; }
            if (v.w > bmax[c]) { bmax[c] = v.w; bidx[c] = base + 3; }
            bsum[c] += __expf(v.x) + __expf(v.y) + __expf(v.z) + __expf(v.w);
        }
        float m = bmax[0]; int idx = bidx[0];
#pragma unroll
        for (int c = 1; c < 4; ++c)               // strict '>': earlier block wins ties
            if (bmax[c] > m) { m = bmax[c]; idx = bidx[c]; }
        const float lse = __logf((bsum[0] + bsum[1]) + (bsum[2] + bsum[3]));
        lpS[s][u] = make_float2(lse, (float)idx);
    }
    // Same-wave producer/consumer through LDS; drain before Phase B reads.
    asm volatile("s_waitcnt lgkmcnt(0)" ::: "memory");

    // ---------- Phase B: fused DP wavefront, operands fetched in-loop -------
    // lane u = column j = u+1 (column 0 analytic). Carried: D|cnt<<8, ce-sum.
    const int     j     = u + 1;
    const float   fl    = (float)lab_u;
    const float*  gcol  = xs + lab_u;       // x[:, lab_u], row stride CCLS
    const float2* lpRow = lpS[s];
    int   prevW = 0;   float prevCE = 0.f;
    int   diagW = 0;   float diagCE = 0.f;
#pragma unroll 8
    for (int d = 1; d <= LROWS + MLAB; ++d) {
        const int   lWs  = dpp_wshr1_i32(prevW);    // (i, j-1)
        const float lCEs = dpp_wshr1_f32(prevCE);
        const int i  = d - j;
        const int ic = min(max(i - 1, 0), LROWS - 1);   // clamped row index
        const float2 lp = lpRow[ic];        // {lse_i, pred_i} — off-chain
        const float  xg = gcol[ic * CCLS];  // x[i-1, lab_u] — off-chain, cache-warm
        // column 0 analytic: D(i,0)=i, cnt=0, ce=0
        const int   lW  = (u == 0) ? max(i, 0)     : lWs;
        const float lCE = (u == 0) ? 0.f           : lCEs;
        const int   dW  = (u == 0) ? max(i - 1, 0) : diagW;
        const float dCE = (u == 0) ? 0.f           : diagCE;
        int curW; float curCE;
        if (i <= 0) {                       // top row: D=j; i<0 lanes inactive
            curW = j; curCE = 0.f;
        } else if (i > LROWS) {             // column finished: hold final value
            curW = prevW; curCE = prevCE;
        } else {
            const int uD = prevW & 255, uC = prevW >> 8;
            const int lD = lW & 255,    lC = lW >> 8;
            const int dD = dW & 255,    dC = dW >> 8;
            const float ce = lp.x - xg;     // lse - x[i-1,lab]  (> 0)
            const int   c  = (lp.y != fl) ? 1 : 0;
            const int nD = min(min(uD, lD) + 1, dD + c);
            // reference backtrace tie-break: diag > up > left
            const bool dg = (dD + c == nD);
            const bool up = !dg && (uD + 1 == nD);
            int nC; float nCE;
            if (dg)      { nC = dC + 1; nCE = dCE + ce; }
            else if (up) { nC = uC;     nCE = prevCE;   }
            else         { nC = lC;     nCE = lCE;      }
            curW = nD | (nC << 8);
            curCE = nCE;
        }
        diagW = lWs; diagCE = lCEs;         // raw shifted value becomes next diag
        prevW = curW; prevCE = curCE;
    }

    // lane u==31 (j=32) holds cell (32,32) after d=64
    if (u == 31) {
        const int cnt = prevW >> 8;
        psum[s] = (cnt > 0) ? prevCE / (float)cnt : 0.f;
        pcnt[s] = (cnt > 0) ? 1.f : 0.f;
    }
    __syncthreads();
    if (threadIdx.x == 0) {
        float ss = 0.f, cc = 0.f;
#pragma unroll
        for (int k = 0; k < SPB; ++k) { ss += psum[k]; cc += pcnt[k]; }
        partial_sum[blockIdx.x] = ss;
        partial_cnt[blockIdx.x] = cc;
    }
}

__global__ __launch_bounds__(256) void editloss_finalize(
    const float* __restrict__ partial_sum, const float* __restrict__ partial_cnt,
    float* __restrict__ out, int nblocks)
{
    float s = 0.f, c = 0.f;
    for (int k = threadIdx.x; k < nblocks; k += 256) {
        s += partial_sum[k];
        c += partial_cnt[k];
    }
#pragma unroll
    for (int d = 32; d >= 1; d >>= 1) {
        s += __shfl_xor(s, d);
        c += __shfl_xor(c, d);
    }
    __shared__ float ss[4], cc[4];
    const int w = threadIdx.x >> 6, lane = threadIdx.x & 63;
    if (lane == 0) { ss[w] = s; cc[w] = c; }
    __syncthreads();
    if (threadIdx.x == 0) {
        const float S  = ss[0] + ss[1] + ss[2] + ss[3];
        const float C2 = cc[0] + cc[1] + cc[2] + cc[3];
        out[0] = (C2 > 0.f) ? (S / C2) : 0.f;
    }
}

extern "C" void kernel_launch(void* const* d_in, const int* in_sizes, int n_in,
                              void* d_out, int out_size, void* d_ws, size_t ws_size,
                              hipStream_t stream) {
    const float* x = (const float*)d_in[0];
    const int*   y = (const int*)d_in[1];
    // d_in[2]=num_chars, d_in[3]=num_labels: constants L/M in this problem.
    float* out = (float*)d_out;

    float* partial_sum = (float*)d_ws;           // NBLK floats
    float* partial_cnt = partial_sum + NBLK;     // NBLK floats

    editloss_main<<<NBLK, 256, 0, stream>>>(x, y, partial_sum, partial_cnt);
    editloss_finalize<<<1, 256, 0, stream>>>(partial_sum, partial_cnt, out, NBLK);
}

// Round 3
// 169.726 us; speedup vs baseline: 1.3407x; 1.3407x over previous
//
#include <hip/hip_runtime.h>
#include <stdint.h>

// Problem constants (from reference setup_inputs)
#define BNUM  8192
#define LROWS 32
#define MLAB  32
#define CCLS  96
#define WPB   4              // waves per block
#define SPW   2              // samples per wave (one per 32-lane half)
#define SPB   (WPB*SPW)      // 8 samples per block
#define NBLK  (BNUM/SPB)     // 1024 blocks

// Design (round 3):
//  P0: 32 per-lane gather loads x[r, lab_u] issued at kernel start into
//      registers (independent of P1; overlaps P1's HBM window; touches the
//      same cache lines P1 fetches -> no extra HBM traffic).
//  P1 (lane-per-row): round-0 code verbatim — 24 dwordx4 loads, 4-way-ILP
//      serial argmax (first-occurrence) + sumexp, zero cross-lane ops.
//      Writes {lse, (float)pred} to lpS.
//  P3: builds sign-encoded ceTab[r][u] from REGISTERS (xg[r]) + lpS.
//      No memory latency on this phase anymore. Same wave as P1 -> no barrier.
//  Phase B: DP wavefront; loop-carried chain now uses DPP wave_shr:1
//      (full-rate VALU lane shift, ~4 cy) instead of ds_bpermute __shfl_up
//      (~50-100 cy DS latency). Correctness of the DPP form verified on HW
//      in round 2 (absmax 0.0). Lanes 0/32 get bound_ctrl zeros, which are
//      overridden by the analytic column-0 injection — identical semantics
//      to the old width-64 __shfl_up.
__device__ __forceinline__ int dpp_wshr1_i32(int v) {
    // dpp_ctrl 0x138 = wave_shr:1
    return __builtin_amdgcn_update_dpp(0, v, 0x138, 0xF, 0xF, true);
}
__device__ __forceinline__ float dpp_wshr1_f32(float v) {
    return __int_as_float(
        __builtin_amdgcn_update_dpp(0, __float_as_int(v), 0x138, 0xF, 0xF, true));
}

__global__ __launch_bounds__(256, 4) void editloss_main(
    const float* __restrict__ x, const int* __restrict__ y,
    float* __restrict__ partial_sum, float* __restrict__ partial_cnt)
{
    __shared__ float  ceTab[SPB][LROWS * MLAB];  // 32 KB
    __shared__ float2 lpS[SPB][LROWS];           // 2 KB: {lse, (float)pred}
    __shared__ float  psum[SPB];
    __shared__ float  pcnt[SPB];

    const int w    = threadIdx.x >> 6;
    const int lane = threadIdx.x & 63;
    const int g    = lane >> 5;          // which sample of the wave
    const int u    = lane & 31;          // slot within 32-lane half
    const int s    = w * SPW + g;        // sample slot in block [0,8)
    const int sb   = blockIdx.x * SPB + s;

    const float* xs    = x + (size_t)sb * (LROWS * CCLS);
    const int    lab_u = y[sb * MLAB + u];

    // ---------- P0: early register gathers for P3 (off the critical path) ---
    float xg[LROWS];
    {
        const float* gcol = xs + lab_u;       // x[:, lab_u], row stride CCLS
#pragma unroll
        for (int r = 0; r < LROWS; ++r) xg[r] = gcol[r * CCLS];
    }

    // ---------- P1: lane-per-row argmax + logsumexp (round-0 verbatim) -----
    {
        const float4* rowv = (const float4*)(xs + (size_t)u * CCLS);
        float bmax[4]; int bidx[4]; float bsum[4];
#pragma unroll
        for (int c = 0; c < 4; ++c) { bmax[c] = -1e30f; bidx[c] = 0; bsum[c] = 0.f; }
#pragma unroll
        for (int c = 0; c < 4; ++c) {         // 4 contiguous blocks of 24 elems
#pragma unroll
            for (int k = 0; k < 6; ++k) {
                const float4 v = rowv[c * 6 + k];
                const int base = (c * 6 + k) * 4;
                // ascending scan, strict '>' keeps first occurrence
                if (v.x > bmax[c]) { bmax[c] = v.x; bidx[c] = base + 0; }
                if (v.y > bmax[c]) { bmax[c] = v.y; bidx[c] = base + 1; }
                if (v.z > bmax[c]) { bmax[c] = v.z; bidx[c] = base + 2; }
                if (v.w > bmax[c]) { bmax[c] = v.w; bidx[c] = base + 3; }
                bsum[c] += __expf(v.x) + __expf(v.y) + __expf(v.z) + __expf(v.w);
            }
        }
        float m = bmax[0]; int idx = bidx[0];
#pragma unroll
        for (int c = 1; c < 4; ++c)           // strict '>': earlier block wins ties
            if (bmax[c] > m) { m = bmax[c]; idx = bidx[c]; }
        const float lse = __logf((bsum[0] + bsum[1]) + (bsum[2] + bsum[3]));
        lpS[s][u] = make_float2(lse, (float)idx);
    }
    // Same-wave producer/consumer; DS pipe is in-order per wave. Drain to be safe.
    asm volatile("s_waitcnt lgkmcnt(0)" ::: "memory");

    // ---------- P3: ceTab build from registers (no memory latency) ----------
    {
        const float fl = (float)lab_u;
#pragma unroll
        for (int r = 0; r < LROWS; ++r) {
            const float2 lp = lpS[s][r];      // wave-uniform per half: broadcast
            const float  ce = lp.x - xg[r];   // strictly > 0
            ceTab[s][r * MLAB + u] = (lp.y == fl) ? ce : -ce;
        }
    }
    asm volatile("s_waitcnt lgkmcnt(0)" ::: "memory");

    // ---------- Phase B: fused DP wavefront (DPP-shift chain) ---------------
    // lane u = column j = u+1 (column 0 analytic). Carried: D|cnt<<8, ce-sum.
    const int j = u + 1;
    int   prevW = 0;   float prevCE = 0.f;
    int   diagW = 0;   float diagCE = 0.f;
#pragma unroll 4
    for (int d = 1; d <= LROWS + MLAB; ++d) {
        const int   lWs  = dpp_wshr1_i32(prevW);    // (i, j-1)
        const float lCEs = dpp_wshr1_f32(prevCE);
        const int i = d - j;
        // column 0 analytic: D(i,0)=i, cnt=0, ce=0
        const int   lW  = (u == 0) ? max(i, 0)     : lWs;
        const float lCE = (u == 0) ? 0.f           : lCEs;
        const int   dW  = (u == 0) ? max(i - 1, 0) : diagW;
        const float dCE = (u == 0) ? 0.f           : diagCE;
        int curW; float curCE;
        if (i <= 0) {                       // top row: D=j; i<0 lanes inactive
            curW = j; curCE = 0.f;
        } else if (i > LROWS) {             // column finished: hold final value
            curW = prevW; curCE = prevCE;
        } else {
            const int uD = prevW & 255, uC = prevW >> 8;
            const int lD = lW & 255,    lC = lW >> 8;
            const int dD = dW & 255,    dC = dW >> 8;
            const float ct  = ceTab[s][(i - 1) * MLAB + u];
            const int   c   = (ct < 0.f) ? 1 : 0;
            const int nD = min(min(uD, lD) + 1, dD + c);
            // reference backtrace tie-break: diag > up > left
            const bool dg = (dD + c == nD);
            const bool up = !dg && (uD + 1 == nD);
            int nC; float nCE;
            if (dg)      { nC = dC + 1; nCE = dCE + fabsf(ct); }
            else if (up) { nC = uC;     nCE = prevCE;          }
            else         { nC = lC;     nCE = lCE;             }
            curW = nD | (nC << 8);
            curCE = nCE;
        }
        diagW = lWs; diagCE = lCEs;         // raw shifted value becomes next diag
        prevW = curW; prevCE = curCE;
    }

    // lane u==31 (j=32) holds cell (32,32) after d=64
    if (u == 31) {
        const int cnt = prevW >> 8;
        psum[s] = (cnt > 0) ? prevCE / (float)cnt : 0.f;
        pcnt[s] = (cnt > 0) ? 1.f : 0.f;
    }
    __syncthreads();
    if (threadIdx.x == 0) {
        float ss = 0.f, cc = 0.f;
#pragma unroll
        for (int k = 0; k < SPB; ++k) { ss += psum[k]; cc += pcnt[k]; }
        partial_sum[blockIdx.x] = ss;
        partial_cnt[blockIdx.x] = cc;
    }
}

__global__ __launch_bounds__(256) void editloss_finalize(
    const float* __restrict__ partial_sum, const float* __restrict__ partial_cnt,
    float* __restrict__ out, int nblocks)
{
    float s = 0.f, c = 0.f;
    for (int k = threadIdx.x; k < nblocks; k += 256) {
        s += partial_sum[k];
        c += partial_cnt[k];
    }
#pragma unroll
    for (int d = 32; d >= 1; d >>= 1) {
        s += __shfl_xor(s, d);
        c += __shfl_xor(c, d);
    }
    __shared__ float ss[4], cc[4];
    const int w = threadIdx.x >> 6, lane = threadIdx.x & 63;
    if (lane == 0) { ss[w] = s; cc[w] = c; }
    __syncthreads();
    if (threadIdx.x == 0) {
        const float S  = ss[0] + ss[1] + ss[2] + ss[3];
        const float C2 = cc[0] + cc[1] + cc[2] + cc[3];
        out[0] = (C2 > 0.f) ? (S / C2) : 0.f;
    }
}

extern "C" void kernel_launch(void* const* d_in, const int* in_sizes, int n_in,
                              void* d_out, int out_size, void* d_ws, size_t ws_size,
                              hipStream_t stream) {
    const float* x = (const float*)d_in[0];
    const int*   y = (const int*)d_in[1];
    // d_in[2]=num_chars, d_in[3]=num_labels: constants L/M in this problem.
    float* out = (float*)d_out;

    float* partial_sum = (float*)d_ws;           // NBLK floats
    float* partial_cnt = partial_sum + NBLK;     // NBLK floats

    editloss_main<<<NBLK, 256, 0, stream>>>(x, y, partial_sum, partial_cnt);
    editloss_finalize<<<1, 256, 0, stream>>>(partial_sum, partial_cnt, out, NBLK);
}

// Round 4
// 166.043 us; speedup vs baseline: 1.3705x; 1.0222x over previous
//
#include <hip/hip_runtime.h>
#include <stdint.h>

// Problem constants (from reference setup_inputs)
#define BNUM  8192
#define LROWS 32
#define MLAB  32
#define CCLS  96
#define WPB   4              // waves per block
#define SPW   2              // samples per wave (one per 32-lane half)
#define SPB   (WPB*SPW)      // 8 samples per block
#define NBLK  (BNUM/SPB)     // 1024 blocks

// Design (round 4):
//  P1 (lane-per-row): lane u owns row u of its half's sample. ALL 24 dwordx4
//     loads are issued back-to-back into va[24] BEFORE any compute: the 8
//     consecutive 16-B requests per 128-B line are simultaneously outstanding,
//     so the L1 MSHRs merge them into one L2 line-request (3 L2 reqs/lane
//     instead of ~24 under the old interleaved schedule, which kept <1 line
//     in flight and thrashed L1 across 16 resident waves). Scan math is
//     bit-identical to the verified round-0 kernel.
//  P3 (lane-per-column): round-0 form — compact warm gathers (64 lanes inside
//     ~6 cache lines per instr, L2-hot right after P1), builds sign-encoded
//     ceTab[r][u]. Same wave as P1 -> no barrier.
//  Phase B: DP wavefront; loop-carried chain uses DPP wave_shr:1 (full-rate
//     VALU lane shift) instead of ds_bpermute __shfl_up. HW-verified exact
//     (round 2, absmax 0.0). Lanes 0/32 bound_ctrl zeros are overridden by
//     the analytic column-0 injection.
__device__ __forceinline__ int dpp_wshr1_i32(int v) {
    // dpp_ctrl 0x138 = wave_shr:1
    return __builtin_amdgcn_update_dpp(0, v, 0x138, 0xF, 0xF, true);
}
__device__ __forceinline__ float dpp_wshr1_f32(float v) {
    return __int_as_float(
        __builtin_amdgcn_update_dpp(0, __float_as_int(v), 0x138, 0xF, 0xF, true));
}

__global__ __launch_bounds__(256, 4) void editloss_main(
    const float* __restrict__ x, const int* __restrict__ y,
    float* __restrict__ partial_sum, float* __restrict__ partial_cnt)
{
    __shared__ float  ceTab[SPB][LROWS * MLAB];  // 32 KB
    __shared__ float2 lpS[SPB][LROWS];           // 2 KB: {lse, (float)pred}
    __shared__ float  psum[SPB];
    __shared__ float  pcnt[SPB];

    const int w    = threadIdx.x >> 6;
    const int lane = threadIdx.x & 63;
    const int g    = lane >> 5;          // which sample of the wave
    const int u    = lane & 31;          // slot within 32-lane half
    const int s    = w * SPW + g;        // sample slot in block [0,8)
    const int sb   = blockIdx.x * SPB + s;

    const float* xs    = x + (size_t)sb * (LROWS * CCLS);
    const int    lab_u = y[sb * MLAB + u];

    // ---------- P1: lane-per-row argmax + logsumexp ------------------------
    {
        const float4* rowv = (const float4*)(xs + (size_t)u * CCLS);
        float bmax[4]; int bidx[4]; float bsum[4];
#pragma unroll
        for (int c = 0; c < 4; ++c) { bmax[c] = -1e30f; bidx[c] = 0; bsum[c] = 0.f; }

        // Issue ALL row loads before any use: same-line requests coalesce in
        // the L1 MSHRs (row is 128-B aligned: f4 0-7 = line0, 8-15 = line1,
        // 16-23 = line2). ~96 VGPRs, fits the 128-reg budget at 4 waves/EU.
        float4 va[24];
#pragma unroll
        for (int t = 0; t < 24; ++t) va[t] = rowv[t];

        // Compute pass: identical element order / block structure / tie-break
        // to the verified round-0 kernel (block c = t/6, ascending scan,
        // strict '>' keeps first occurrence).
#pragma unroll
        for (int t = 0; t < 24; ++t) {
            const int c = t / 6;                  // compile-time per unrolled t
            const float4 v = va[t];
            const int base = t * 4;
            if (v.x > bmax[c]) { bmax[c] = v.x; bidx[c] = base + 0; }
            if (v.y > bmax[c]) { bmax[c] = v.y; bidx[c] = base + 1; }
            if (v.z > bmax[c]) { bmax[c] = v.z; bidx[c] = base + 2; }
            if (v.w > bmax[c]) { bmax[c] = v.w; bidx[c] = base + 3; }
            bsum[c] += __expf(v.x) + __expf(v.y) + __expf(v.z) + __expf(v.w);
        }
        float m = bmax[0]; int idx = bidx[0];
#pragma unroll
        for (int c = 1; c < 4; ++c)           // strict '>': earlier block wins ties
            if (bmax[c] > m) { m = bmax[c]; idx = bidx[c]; }
        const float lse = __logf((bsum[0] + bsum[1]) + (bsum[2] + bsum[3]));
        lpS[s][u] = make_float2(lse, (float)idx);
    }
    // Same-wave producer/consumer; DS pipe is in-order per wave. Drain to be safe.
    asm volatile("s_waitcnt lgkmcnt(0)" ::: "memory");

    // ---------- P3: lane-per-column ceTab build (compact warm gathers) ------
    {
        const float* gcol = xs + lab_u;       // stride CCLS floats
#pragma unroll
        for (int r = 0; r < LROWS; ++r) {
            const float2 lp = lpS[s][r];      // wave-uniform per half: broadcast
            const float  xg = gcol[r * CCLS]; // L2-warm gather (~6 lines/instr)
            const float  ce = lp.x - xg;      // strictly > 0
            ceTab[s][r * MLAB + u] = ((int)lp.y == lab_u) ? ce : -ce;
        }
    }
    asm volatile("s_waitcnt lgkmcnt(0)" ::: "memory");

    // ---------- Phase B: fused DP wavefront (DPP-shift chain) ---------------
    // lane u = column j = u+1 (column 0 analytic). Carried: D|cnt<<8, ce-sum.
    const int j = u + 1;
    int   prevW = 0;   float prevCE = 0.f;
    int   diagW = 0;   float diagCE = 0.f;
#pragma unroll 4
    for (int d = 1; d <= LROWS + MLAB; ++d) {
        const int   lWs  = dpp_wshr1_i32(prevW);    // (i, j-1)
        const float lCEs = dpp_wshr1_f32(prevCE);
        const int i = d - j;
        // column 0 analytic: D(i,0)=i, cnt=0, ce=0
        const int   lW  = (u == 0) ? max(i, 0)     : lWs;
        const float lCE = (u == 0) ? 0.f           : lCEs;
        const int   dW  = (u == 0) ? max(i - 1, 0) : diagW;
        const float dCE = (u == 0) ? 0.f           : diagCE;
        int curW; float curCE;
        if (i <= 0) {                       // top row: D=j; i<0 lanes inactive
            curW = j; curCE = 0.f;
        } else if (i > LROWS) {             // column finished: hold final value
            curW = prevW; curCE = prevCE;
        } else {
            const int uD = prevW & 255, uC = prevW >> 8;
            const int lD = lW & 255,    lC = lW >> 8;
            const int dD = dW & 255,    dC = dW >> 8;
            const float ct  = ceTab[s][(i - 1) * MLAB + u];
            const int   c   = (ct < 0.f) ? 1 : 0;
            const int nD = min(min(uD, lD) + 1, dD + c);
            // reference backtrace tie-break: diag > up > left
            const bool dg = (dD + c == nD);
            const bool up = !dg && (uD + 1 == nD);
            int nC; float nCE;
            if (dg)      { nC = dC + 1; nCE = dCE + fabsf(ct); }
            else if (up) { nC = uC;     nCE = prevCE;          }
            else         { nC = lC;     nCE = lCE;             }
            curW = nD | (nC << 8);
            curCE = nCE;
        }
        diagW = lWs; diagCE = lCEs;         // raw shifted value becomes next diag
        prevW = curW; prevCE = curCE;
    }

    // lane u==31 (j=32) holds cell (32,32) after d=64
    if (u == 31) {
        const int cnt = prevW >> 8;
        psum[s] = (cnt > 0) ? prevCE / (float)cnt : 0.f;
        pcnt[s] = (cnt > 0) ? 1.f : 0.f;
    }
    __syncthreads();
    if (threadIdx.x == 0) {
        float ss = 0.f, cc = 0.f;
#pragma unroll
        for (int k = 0; k < SPB; ++k) { ss += psum[k]; cc += pcnt[k]; }
        partial_sum[blockIdx.x] = ss;
        partial_cnt[blockIdx.x] = cc;
    }
}

__global__ __launch_bounds__(256) void editloss_finalize(
    const float* __restrict__ partial_sum, const float* __restrict__ partial_cnt,
    float* __restrict__ out, int nblocks)
{
    float s = 0.f, c = 0.f;
    for (int k = threadIdx.x; k < nblocks; k += 256) {
        s += partial_sum[k];
        c += partial_cnt[k];
    }
#pragma unroll
    for (int d = 32; d >= 1; d >>= 1) {
        s += __shfl_xor(s, d);
        c += __shfl_xor(c, d);
    }
    __shared__ float ss[4], cc[4];
    const int w = threadIdx.x >> 6, lane = threadIdx.x & 63;
    if (lane == 0) { ss[w] = s; cc[w] = c; }
    __syncthreads();
    if (threadIdx.x == 0) {
        const float S  = ss[0] + ss[1] + ss[2] + ss[3];
        const float C2 = cc[0] + cc[1] + cc[2] + cc[3];
        out[0] = (C2 > 0.f) ? (S / C2) : 0.f;
    }
}

extern "C" void kernel_launch(void* const* d_in, const int* in_sizes, int n_in,
                              void* d_out, int out_size, void* d_ws, size_t ws_size,
                              hipStream_t stream) {
    const float* x = (const float*)d_in[0];
    const int*   y = (const int*)d_in[1];
    // d_in[2]=num_chars, d_in[3]=num_labels: constants L/M in this problem.
    float* out = (float*)d_out;

    float* partial_sum = (float*)d_ws;           // NBLK floats
    float* partial_cnt = partial_sum + NBLK;     // NBLK floats

    editloss_main<<<NBLK, 256, 0, stream>>>(x, y, partial_sum, partial_cnt);
    editloss_finalize<<<1, 256, 0, stream>>>(partial_sum, partial_cnt, out, NBLK);
}